// Round 1
// baseline (347.143 us; speedup 1.0000x reference)
//
#include <hip/hip_runtime.h>

#define CH 512
#define HEADS 4
#define HD 128
#define NPIX 1024
#define BATCH 16
#define GROUPS 32
#define GSZ 16
#define EPS 1e-5f

typedef _Float16 f16;
typedef _Float16 f16x8 __attribute__((ext_vector_type(8)));
typedef _Float16 f16x4 __attribute__((ext_vector_type(4)));
typedef float f32x4 __attribute__((ext_vector_type(4)));

// ---------------- K0: convert weights fp32 -> fp16 ----------------
__global__ void k_convert(const float* __restrict__ wq, const float* __restrict__ wp,
                          f16* __restrict__ wq16, f16* __restrict__ wp16) {
    int i = blockIdx.x * 256 + threadIdx.x;
    if (i < 3 * CH * CH) wq16[i] = (f16)wq[i];
    if (i < CH * CH)     wp16[i] = (f16)wp[i];
}

// ---------------- K1a: groupnorm stats (mean, rstd) per (b,g) ----------------
__global__ void k_stats(const float* __restrict__ x, float2* __restrict__ stats) {
    int bg = blockIdx.x; // b*GROUPS+g ; group data is contiguous: 16 ch * 1024
    const f32x4* b4 = (const f32x4*)(x + (size_t)bg * (GSZ * NPIX));
    float s = 0.f, ss = 0.f;
    for (int i = threadIdx.x; i < GSZ * NPIX / 4; i += 256) {
        f32x4 v = b4[i];
        s  += v.x + v.y + v.z + v.w;
        ss += v.x * v.x + v.y * v.y + v.z * v.z + v.w * v.w;
    }
    for (int off = 32; off; off >>= 1) { s += __shfl_down(s, off); ss += __shfl_down(ss, off); }
    __shared__ float as_[4], ass[4];
    int wv = threadIdx.x >> 6, ln = threadIdx.x & 63;
    if (ln == 0) { as_[wv] = s; ass[wv] = ss; }
    __syncthreads();
    if (threadIdx.x == 0) {
        float S = as_[0] + as_[1] + as_[2] + as_[3];
        float SS = ass[0] + ass[1] + ass[2] + ass[3];
        float mu = S / (GSZ * NPIX);
        float var = SS / (GSZ * NPIX) - mu * mu;
        stats[bg] = make_float2(mu, rsqrtf(var + EPS));
    }
}

// ---------------- K1b: normalize + transpose -> xnT[b][n][c] fp16 ----------------
__global__ void k_norm_t(const float* __restrict__ x, const float* __restrict__ gamma,
                         const float* __restrict__ beta, const float2* __restrict__ stats,
                         f16* __restrict__ xnT) {
    int nt = blockIdx.x, b = blockIdx.y;
    int n0 = nt * 128;
    __shared__ float gS[CH], bS[CH];
    __shared__ float2 stS[GROUPS];
    __shared__ f16 TT[64][136];
    for (int i = threadIdx.x; i < CH; i += 256) { gS[i] = gamma[i]; bS[i] = beta[i]; }
    if (threadIdx.x < GROUPS) stS[threadIdx.x] = stats[b * GROUPS + threadIdx.x];
    __syncthreads();
    for (int cc = 0; cc < CH; cc += 64) {
        __syncthreads();
        for (int i = 0; i < 8; i++) {
            int cid = threadIdx.x + i * 256;
            int c = cid >> 5;            // 32 float4 per 128-wide row
            int n = (cid & 31) * 4;
            int cg = cc + c;
            f32x4 v = *(const f32x4*)(x + ((size_t)(b * CH + cg)) * NPIX + n0 + n);
            float2 st = stS[cg >> 4];
            float g = gS[cg] * st.y;
            float bb = bS[cg] - st.x * g;
            f16x4 h;
            h[0] = (f16)(v.x * g + bb); h[1] = (f16)(v.y * g + bb);
            h[2] = (f16)(v.z * g + bb); h[3] = (f16)(v.w * g + bb);
            *(f16x4*)&TT[c][n] = h;
        }
        __syncthreads();
        for (int i = 0; i < 4; i++) {
            int cid = threadIdx.x + i * 256;
            int n = cid >> 3;
            int k8 = (cid & 7) * 8;
            f16x8 v;
            for (int j = 0; j < 8; j++) v[j] = TT[k8 + j][n];
            *(f16x8*)(xnT + ((size_t)(b * NPIX) + n0 + n) * CH + cc + k8) = v;
        }
    }
}

// ---------------- K2: QKV GEMM (fp16 MFMA), writes qT/kT [b][h][n][d], vN [b][h][d][m] ----------------
__global__ __launch_bounds__(256, 2) void k_qkv(const f16* __restrict__ w16, const float* __restrict__ bias,
                                                const f16* __restrict__ xnT, f16* __restrict__ qT,
                                                f16* __restrict__ kT, f16* __restrict__ vN) {
    int nt = blockIdx.x, ot = blockIdx.y, b = blockIdx.z;
    int n0 = nt * 128, o0 = ot * 128;
    __shared__ union SM {
        struct { f16 A[128][40]; f16 Bt[128][40]; } s;
        f16 Cs[128][136];
    } sm;
    __shared__ float biasS[128];
    if (threadIdx.x < 128) biasS[threadIdx.x] = bias[o0 + threadIdx.x];
    int lane = threadIdx.x & 63, wv = threadIdx.x >> 6;
    int wr = wv >> 1, wc = wv & 1;
    int l15 = lane & 15, quad = lane >> 4;
    f32x4 acc[4][4] = {};
    for (int kk = 0; kk < CH; kk += 32) {
        __syncthreads();
        for (int i = 0; i < 2; i++) {
            int cid = threadIdx.x + i * 256;
            int row = cid >> 2, off = (cid & 3) * 8;
            *(f16x8*)&sm.s.A[row][off]  = *(const f16x8*)(w16 + (size_t)(o0 + row) * CH + kk + off);
            *(f16x8*)&sm.s.Bt[row][off] = *(const f16x8*)(xnT + ((size_t)(b * NPIX) + n0 + row) * CH + kk + off);
        }
        __syncthreads();
        f16x8 af[4], bf[4];
        for (int t = 0; t < 4; t++) {
            af[t] = *(const f16x8*)&sm.s.A[wr * 64 + t * 16 + l15][quad * 8];
            bf[t] = *(const f16x8*)&sm.s.Bt[wc * 64 + t * 16 + l15][quad * 8];
        }
        for (int tm = 0; tm < 4; tm++)
            for (int tn = 0; tn < 4; tn++)
                acc[tm][tn] = __builtin_amdgcn_mfma_f32_16x16x32_f16(af[tm], bf[tn], acc[tm][tn], 0, 0, 0);
    }
    __syncthreads();
    int which = ot >> 2, h = ot & 3;
    for (int tm = 0; tm < 4; tm++)
        for (int tn = 0; tn < 4; tn++)
            for (int r = 0; r < 4; r++) {
                int o = wr * 64 + tm * 16 + quad * 4 + r;
                int n = wc * 64 + tn * 16 + l15;
                float v = acc[tm][tn][r] + biasS[o];
                if (which < 2) sm.Cs[n][o] = (f16)v;   // transposed store for q,k
                else           sm.Cs[o][n] = (f16)v;   // natural for v
            }
    __syncthreads();
    f16* dst = (which == 0) ? qT : (which == 1) ? kT : vN;
    for (int i = 0; i < 8; i++) {
        int cid = threadIdx.x + i * 256;
        int row = cid >> 4, off = (cid & 15) * 8;
        f16x8 v = *(f16x8*)&sm.Cs[row][off];
        if (which < 2)
            *(f16x8*)(dst + (((size_t)(b * HEADS + h)) * NPIX + n0 + row) * HD + off) = v;
        else
            *(f16x8*)(dst + (((size_t)(b * HEADS + h)) * HD + row) * NPIX + n0 + off) = v;
    }
}

// ---------------- K3: flash attention, one block per (b,h,n-tile of 128) ----------------
__global__ __launch_bounds__(256, 1) void k_attn(const f16* __restrict__ qT, const f16* __restrict__ kT,
                                                 const f16* __restrict__ vN, f16* __restrict__ attnT) {
    int nt = blockIdx.x, h = blockIdx.y, b = blockIdx.z;
    int n0 = nt * 128;
    extern __shared__ f16 smem[];
    f16 (*QsT)[136] = (f16(*)[136])smem;                   // [n][d]
    f16 (*KsT)[136] = (f16(*)[136])(smem + 128 * 136);     // [m][d]
    f16 (*Vs)[136]  = (f16(*)[136])(smem + 2 * 128 * 136); // [c][m]
    f16 (*Ps)[136]  = (f16(*)[136])(smem + 3 * 128 * 136); // [n][m] then reused [n][c]
    const f16* qb = qT + ((size_t)(b * HEADS + h)) * NPIX * HD;
    const f16* kb = kT + ((size_t)(b * HEADS + h)) * NPIX * HD;
    const f16* vb = vN + ((size_t)(b * HEADS + h)) * HD * NPIX;
    int lane = threadIdx.x & 63, wv = threadIdx.x >> 6;
    int l15 = lane & 15, quad = lane >> 4;
    for (int i = 0; i < 8; i++) {
        int cid = threadIdx.x + i * 256;
        int row = cid >> 4, off = (cid & 15) * 8;
        *(f16x8*)&QsT[row][off] = *(const f16x8*)(qb + (size_t)(n0 + row) * HD + off);
    }
    float m_i[2][4], l_i[2][4];
    for (int t = 0; t < 2; t++) for (int r = 0; r < 4; r++) { m_i[t][r] = -1e30f; l_i[t][r] = 0.f; }
    f32x4 oacc[2][8] = {};
    const float scale = 0.08838834764831845f; // 1/sqrt(128)
    for (int mc = 0; mc < 8; mc++) {
        int m0 = mc * 128;
        __syncthreads();
        for (int i = 0; i < 8; i++) {
            int cid = threadIdx.x + i * 256;
            int row = cid >> 4, off = (cid & 15) * 8;
            *(f16x8*)&KsT[row][off] = *(const f16x8*)(kb + (size_t)(m0 + row) * HD + off);
            *(f16x8*)&Vs[row][off]  = *(const f16x8*)(vb + (size_t)row * NPIX + m0 + off);
        }
        __syncthreads();
        // S = Q^T K for wave's 32 n-rows x 128 m
        f32x4 sacc[2][8] = {};
        for (int dk = 0; dk < 4; dk++) {
            f16x8 aq[2], bk[8];
            for (int t = 0; t < 2; t++) aq[t] = *(const f16x8*)&QsT[wv * 32 + t * 16 + l15][dk * 32 + quad * 8];
            for (int t = 0; t < 8; t++) bk[t] = *(const f16x8*)&KsT[t * 16 + l15][dk * 32 + quad * 8];
            for (int tr = 0; tr < 2; tr++)
                for (int tc = 0; tc < 8; tc++)
                    sacc[tr][tc] = __builtin_amdgcn_mfma_f32_16x16x32_f16(aq[tr], bk[tc], sacc[tr][tc], 0, 0, 0);
        }
        // online softmax
        for (int tr = 0; tr < 2; tr++) {
            for (int r = 0; r < 4; r++) {
                float mx = -1e30f;
                for (int tc = 0; tc < 8; tc++) { sacc[tr][tc][r] *= scale; mx = fmaxf(mx, sacc[tr][tc][r]); }
                for (int d = 1; d < 16; d <<= 1) mx = fmaxf(mx, __shfl_xor(mx, d, 16));
                float mnew = fmaxf(m_i[tr][r], mx);
                float alpha = __expf(m_i[tr][r] - mnew);
                m_i[tr][r] = mnew;
                float rs = 0.f;
                for (int tc = 0; tc < 8; tc++) {
                    float p = __expf(sacc[tr][tc][r] - mnew);
                    sacc[tr][tc][r] = p;
                    rs += p;
                }
                for (int d = 1; d < 16; d <<= 1) rs += __shfl_xor(rs, d, 16);
                l_i[tr][r] = l_i[tr][r] * alpha + rs;
                for (int tc = 0; tc < 8; tc++) oacc[tr][tc][r] *= alpha;
                int n = wv * 32 + tr * 16 + quad * 4 + r;
                for (int tc = 0; tc < 8; tc++) Ps[n][tc * 16 + l15] = (f16)sacc[tr][tc][r];
            }
        }
        // O += P V^T  (A = Ps rows n, B[k=m][c] = Vs[c][m])
        for (int mk = 0; mk < 4; mk++) {
            f16x8 ap[2], bv[8];
            for (int t = 0; t < 2; t++) ap[t] = *(const f16x8*)&Ps[wv * 32 + t * 16 + l15][mk * 32 + quad * 8];
            for (int t = 0; t < 8; t++) bv[t] = *(const f16x8*)&Vs[t * 16 + l15][mk * 32 + quad * 8];
            for (int tr = 0; tr < 2; tr++)
                for (int tc = 0; tc < 8; tc++)
                    oacc[tr][tc] = __builtin_amdgcn_mfma_f32_16x16x32_f16(ap[tr], bv[tc], oacc[tr][tc], 0, 0, 0);
        }
    }
    // epilogue: O/l -> Ps[n][c] -> coalesced global [n][c]
    for (int tr = 0; tr < 2; tr++)
        for (int r = 0; r < 4; r++) {
            float inv = 1.f / l_i[tr][r];
            int n = wv * 32 + tr * 16 + quad * 4 + r;
            for (int tc = 0; tc < 8; tc++) Ps[n][tc * 16 + l15] = (f16)(oacc[tr][tc][r] * inv);
        }
    __syncthreads();
    for (int i = 0; i < 8; i++) {
        int cid = threadIdx.x + i * 256;
        int row = cid >> 4, off = (cid & 15) * 8;
        *(f16x8*)(attnT + ((size_t)(b * NPIX) + n0 + row) * CH + h * HD + off) = *(f16x8*)&Ps[row][off];
    }
}

// ---------------- K4: proj GEMM + bias + residual -> fp32 out ----------------
__global__ __launch_bounds__(256, 2) void k_proj(const f16* __restrict__ w16, const float* __restrict__ bias,
                                                 const f16* __restrict__ attnT, const float* __restrict__ x,
                                                 float* __restrict__ out) {
    int nt = blockIdx.x, ot = blockIdx.y, b = blockIdx.z;
    int n0 = nt * 128, o0 = ot * 128;
    __shared__ union SM {
        struct { f16 A[128][40]; f16 Bt[128][40]; } s;
        f16 Cs[128][136];
    } sm;
    __shared__ float biasS[128];
    if (threadIdx.x < 128) biasS[threadIdx.x] = bias[o0 + threadIdx.x];
    int lane = threadIdx.x & 63, wv = threadIdx.x >> 6;
    int wr = wv >> 1, wc = wv & 1;
    int l15 = lane & 15, quad = lane >> 4;
    f32x4 acc[4][4] = {};
    for (int kk = 0; kk < CH; kk += 32) {
        __syncthreads();
        for (int i = 0; i < 2; i++) {
            int cid = threadIdx.x + i * 256;
            int row = cid >> 2, off = (cid & 3) * 8;
            *(f16x8*)&sm.s.A[row][off]  = *(const f16x8*)(w16 + (size_t)(o0 + row) * CH + kk + off);
            *(f16x8*)&sm.s.Bt[row][off] = *(const f16x8*)(attnT + ((size_t)(b * NPIX) + n0 + row) * CH + kk + off);
        }
        __syncthreads();
        f16x8 af[4], bf[4];
        for (int t = 0; t < 4; t++) {
            af[t] = *(const f16x8*)&sm.s.A[wr * 64 + t * 16 + l15][quad * 8];
            bf[t] = *(const f16x8*)&sm.s.Bt[wc * 64 + t * 16 + l15][quad * 8];
        }
        for (int tm = 0; tm < 4; tm++)
            for (int tn = 0; tn < 4; tn++)
                acc[tm][tn] = __builtin_amdgcn_mfma_f32_16x16x32_f16(af[tm], bf[tn], acc[tm][tn], 0, 0, 0);
    }
    __syncthreads();
    for (int tm = 0; tm < 4; tm++)
        for (int tn = 0; tn < 4; tn++)
            for (int r = 0; r < 4; r++) {
                int o = wr * 64 + tm * 16 + quad * 4 + r;
                int n = wc * 64 + tn * 16 + l15;
                sm.Cs[o][n] = (f16)(acc[tm][tn][r] + biasS[o]);
            }
    __syncthreads();
    for (int i = 0; i < 8; i++) {
        int cid = threadIdx.x + i * 256;
        int row = cid >> 4, off = (cid & 15) * 8;
        f16x8 v = *(f16x8*)&sm.Cs[row][off];
        size_t gofs = ((size_t)(b * CH) + o0 + row) * NPIX + n0 + off;
        const float* xp = x + gofs;
        float* op = out + gofs;
        f32x4 o0v, o1v;
        o0v.x = xp[0] + (float)v[0]; o0v.y = xp[1] + (float)v[1];
        o0v.z = xp[2] + (float)v[2]; o0v.w = xp[3] + (float)v[3];
        o1v.x = xp[4] + (float)v[4]; o1v.y = xp[5] + (float)v[5];
        o1v.z = xp[6] + (float)v[6]; o1v.w = xp[7] + (float)v[7];
        *(f32x4*)op = o0v; *(f32x4*)(op + 4) = o1v;
    }
}

extern "C" void kernel_launch(void* const* d_in, const int* in_sizes, int n_in,
                              void* d_out, int out_size, void* d_ws, size_t ws_size,
                              hipStream_t stream) {
    const float* x     = (const float*)d_in[0];
    const float* gamma = (const float*)d_in[1];
    const float* beta  = (const float*)d_in[2];
    const float* wqkv  = (const float*)d_in[3];
    const float* bqkv  = (const float*)d_in[4];
    const float* wproj = (const float*)d_in[5];
    const float* bproj = (const float*)d_in[6];
    float* out = (float*)d_out;

    char* p = (char*)d_ws;
    float2* stats = (float2*)p;          p += 16 * 32 * sizeof(float2);
    f16* wq16 = (f16*)p;                 p += (size_t)3 * CH * CH * 2;
    f16* wp16 = (f16*)p;                 p += (size_t)CH * CH * 2;
    f16* xnT  = (f16*)p;                 p += (size_t)BATCH * NPIX * CH * 2;
    f16* qT   = (f16*)p;                 p += (size_t)BATCH * HEADS * NPIX * HD * 2;
    f16* kT   = (f16*)p;                 p += (size_t)BATCH * HEADS * NPIX * HD * 2;
    f16* vN   = (f16*)p;                 p += (size_t)BATCH * HEADS * HD * NPIX * 2;
    f16* attnT = (f16*)p;                p += (size_t)BATCH * NPIX * CH * 2;

    k_convert<<<dim3((3 * CH * CH + 255) / 256), 256, 0, stream>>>(wqkv, wproj, wq16, wp16);
    k_stats<<<dim3(BATCH * GROUPS), 256, 0, stream>>>(x, stats);
    k_norm_t<<<dim3(8, BATCH), 256, 0, stream>>>(x, gamma, beta, stats, xnT);
    k_qkv<<<dim3(8, 12, BATCH), 256, 0, stream>>>(wq16, bqkv, xnT, qT, kT, vN);

    static bool attr_set = false;
    (void)attr_set;
    hipFuncSetAttribute((const void*)k_attn, hipFuncAttributeMaxDynamicSharedMemorySize, 4 * 128 * 136 * 2);
    k_attn<<<dim3(8, HEADS, BATCH), 256, 4 * 128 * 136 * 2, stream>>>(qT, kT, vN, attnT);

    k_proj<<<dim3(8, 4, BATCH), 256, 0, stream>>>(wp16, bproj, attnT, x, out);
}